// Round 7
// baseline (266.542 us; speedup 1.0000x reference)
//
#include <hip/hip_runtime.h>
#include <hip/hip_bf16.h>
#include <math.h>

typedef __attribute__((ext_vector_type(8))) short short8;
typedef __attribute__((ext_vector_type(4))) float floatx4;
typedef __attribute__((ext_vector_type(16))) float floatx16;
typedef __attribute__((ext_vector_type(4))) unsigned short ushort4v;
typedef unsigned long long u64;

__device__ __forceinline__ unsigned short f32_to_bf16(float f) {
    union { float f; unsigned int u; } v; v.f = f;
    return (unsigned short)((v.u + 0x7fffu + ((v.u >> 16) & 1u)) >> 16);
}
__device__ __forceinline__ unsigned pack_bf16x2(float a, float b) {
    __hip_bfloat162 h = __float22bfloat162_rn(make_float2(a, b));
    union { __hip_bfloat162 h; unsigned u; } c; c.h = h; return c.u;
}

#define GL2LDS16(g, l)                                                        \
    __builtin_amdgcn_global_load_lds(                                         \
        (const __attribute__((address_space(1))) unsigned int*)(g),           \
        (__attribute__((address_space(3))) unsigned int*)(l), 16, 0, 0)

// XOR-swizzle: within each 64-elem chunk, physical 8-group = logical ^ (row&7)
__device__ __forceinline__ int swz(int k, int row) {
    return (k & ~63) | (k & 7) | ((((k >> 3) ^ row) & 7) << 3);
}

// log2(e)/32: folds exp->exp2 and the 1/sqrt(1024) scale into Q
#define QSCALE 0.04508422002f

// ---------------------------------------------------------------------------
// prep: all six f32->bf16 swizzled conversions AND mask->bitmask, one launch.
// blocks [0,12288): cvt rows (Q 4096, K 4096, weights 4x1024).
// blocks [12288,45056): maskbits.
// ---------------------------------------------------------------------------
__global__ __launch_bounds__(256)
void prep(const float* __restrict__ Q, const float* __restrict__ K,
          const float* __restrict__ Wq, const float* __restrict__ Wk,
          const float* __restrict__ Wv, const float* __restrict__ Wo,
          const int* __restrict__ mask,
          unsigned short* __restrict__ Qc, unsigned short* __restrict__ Kc,
          unsigned short* __restrict__ Wqc, unsigned short* __restrict__ Wkc,
          unsigned short* __restrict__ Wvc, unsigned short* __restrict__ Woc,
          u64* __restrict__ Mb) {
    const int r = blockIdx.x;
    if (r < 12288) {
        const float* src; unsigned short* dst; int row;
        if (r < 4096)      { src = Q; dst = Qc; row = r; }
        else if (r < 8192) { src = K; dst = Kc; row = r - 4096; }
        else {
            const int t = r - 8192; const int wi = t >> 10; row = t & 1023;
            src = (wi == 0) ? Wq : (wi == 1) ? Wk : (wi == 2) ? Wv : Wo;
            dst = (wi == 0) ? Wqc : (wi == 1) ? Wkc : (wi == 2) ? Wvc : Woc;
        }
        const int k = threadIdx.x * 4;
        floatx4 v = *(const floatx4*)(src + (size_t)row * 1024 + k);
        ushort4v o;
        #pragma unroll
        for (int j = 0; j < 4; j++) o[j] = f32_to_bf16(v[j]);
        *(ushort4v*)(dst + (size_t)row * 1024 + swz(k, row)) = o;
    } else {
        const int gid = (r - 12288) * 256 + threadIdx.x;
        const int v = mask[gid];
        u64 bal = __ballot(v != 0);
        if ((threadIdx.x & 63) == 0) Mb[gid >> 6] = bal;
    }
}

// ---------------------------------------------------------------------------
// Three projection GEMMs, one launch (grid.z): 128x128 tile, BK=64,
// 32x32x16 MFMA (wave = 64x64 via 2x2 floatx16 accs). 768 blocks.
// z=0: Qp = (Qc Wq^T + bq) * QSCALE; z=1: Kp; z=2: Vtp (transposed out).
// ---------------------------------------------------------------------------
__global__ __launch_bounds__(256)
void proj3(const unsigned short* __restrict__ Qc, const unsigned short* __restrict__ Kc,
           const unsigned short* __restrict__ Wq, const unsigned short* __restrict__ Wk,
           const unsigned short* __restrict__ Wv,
           const float* __restrict__ bq, const float* __restrict__ bk,
           const float* __restrict__ bv,
           unsigned short* __restrict__ Qp, unsigned short* __restrict__ Kp,
           unsigned short* __restrict__ Vtp) {
    constexpr int K = 1024;
    const int z = blockIdx.z;
    const unsigned short* A = (z == 0) ? Qc : Kc;
    const unsigned short* W = (z == 0) ? Wq : (z == 1) ? Wk : Wv;
    const float* bias = (z == 0) ? bq : (z == 1) ? bk : bv;

    __shared__ unsigned short As[128 * 64];
    __shared__ unsigned short Ws[128 * 64];

    const int tid = threadIdx.x;
    const int w = tid >> 6, lane = tid & 63;
    const int col = lane & 31, hi = lane >> 5;
    const int m0 = blockIdx.x * 128, n0 = blockIdx.y * 128;
    const int wm = (w >> 1) * 64, wn = (w & 1) * 64;

    floatx16 acc[2][2];
    #pragma unroll
    for (int tm = 0; tm < 2; tm++)
        #pragma unroll
        for (int tn = 0; tn < 2; tn++)
            acc[tm][tn] = (floatx16){0,0,0,0,0,0,0,0,0,0,0,0,0,0,0,0};

    const int lrow = lane >> 3, lcol = (lane & 7) * 8;
    const unsigned short* Ag = A + (size_t)(m0 + w * 32 + lrow) * K + lcol;
    const unsigned short* Wg = W + (size_t)(n0 + w * 32 + lrow) * K + lcol;

    int fo[4];
    #pragma unroll
    for (int c = 0; c < 4; c++) fo[c] = ((c * 2 + hi) ^ (col & 7)) * 8;

    for (int kb = 0; kb < K; kb += 64) {
        __syncthreads();
        #pragma unroll
        for (int i = 0; i < 4; i++) {
            GL2LDS16(Ag + (size_t)(i * 8) * K + kb, &As[(w * 32 + i * 8) * 64]);
            GL2LDS16(Wg + (size_t)(i * 8) * K + kb, &Ws[(w * 32 + i * 8) * 64]);
        }
        __syncthreads();

        #pragma unroll
        for (int kc = 0; kc < 4; kc++) {
            short8 af0 = *(const short8*)&As[(wm + col) * 64 + fo[kc]];
            short8 af1 = *(const short8*)&As[(wm + 32 + col) * 64 + fo[kc]];
            short8 wf0 = *(const short8*)&Ws[(wn + col) * 64 + fo[kc]];
            short8 wf1 = *(const short8*)&Ws[(wn + 32 + col) * 64 + fo[kc]];
            acc[0][0] = __builtin_amdgcn_mfma_f32_32x32x16_bf16(af0, wf0, acc[0][0], 0, 0, 0);
            acc[0][1] = __builtin_amdgcn_mfma_f32_32x32x16_bf16(af0, wf1, acc[0][1], 0, 0, 0);
            acc[1][0] = __builtin_amdgcn_mfma_f32_32x32x16_bf16(af1, wf0, acc[1][0], 0, 0, 0);
            acc[1][1] = __builtin_amdgcn_mfma_f32_32x32x16_bf16(af1, wf1, acc[1][1], 0, 0, 0);
        }
    }

    #pragma unroll
    for (int tn = 0; tn < 2; tn++) {
        const int n = n0 + wn + tn * 32 + col;
        const float bb = bias[n];
        const int ng = (n >> 3) & 7;
        #pragma unroll
        for (int tm = 0; tm < 2; tm++) {
            #pragma unroll
            for (int rg = 0; rg < 4; rg++) {
                const int mbase = m0 + wm + tm * 32 + rg * 8 + 4 * hi;
                if (z == 2) {
                    const int bidx = mbase >> 11;
                    const int t = mbase & 2047;
                    const int mg = (mbase >> 3) & 7;
                    ushort4v o;
                    #pragma unroll
                    for (int r = 0; r < 4; r++)
                        o[r] = f32_to_bf16(acc[tm][tn][rg * 4 + r] + bb);
                    *(ushort4v*)(Vtp + ((size_t)(bidx * 1024 + n)) * 2048 +
                                 (t & ~63) + ((mg ^ (n & 7)) * 8) + (t & 7)) = o;
                } else {
                    unsigned short* outp = (z == 0) ? Qp : Kp;
                    const float sc = (z == 0) ? QSCALE : 1.0f;
                    #pragma unroll
                    for (int r = 0; r < 4; r++) {
                        const int m = mbase + r;
                        const int pn = (n & ~63) | (((ng ^ (m & 7)) & 7) << 3) | (n & 7);
                        outp[(size_t)m * 1024 + pn] =
                            f32_to_bf16((acc[tm][tn][rg * 4 + r] + bb) * sc);
                    }
                }
            }
        }
    }
}

// ---------------------------------------------------------------------------
// Output projection: f32 out, A/W bf16-swizzled. 128x64 tile (512 blocks).
// ---------------------------------------------------------------------------
__global__ __launch_bounds__(256)
void gemm_o(const unsigned short* __restrict__ A, const unsigned short* __restrict__ W,
            const float* __restrict__ bias, float* __restrict__ out) {
    constexpr int K = 1024, N = 1024;
    __shared__ unsigned short As[128 * 64];
    __shared__ unsigned short Ws[64 * 64];

    const int tid = threadIdx.x;
    const int w = tid >> 6, lane = tid & 63;
    const int col = lane & 15, quad = lane >> 4;
    const int m0 = blockIdx.x * 128, n0 = blockIdx.y * 64;

    floatx4 acc[2][4];
    #pragma unroll
    for (int t = 0; t < 2; t++)
        #pragma unroll
        for (int u = 0; u < 4; u++) acc[t][u] = (floatx4){0.f, 0.f, 0.f, 0.f};

    const int lrow = lane >> 3, lcol = (lane & 7) * 8;
    const unsigned short* Ag = A + (size_t)(m0 + w * 32 + lrow) * K + lcol;
    const unsigned short* Wg = W + (size_t)(n0 + w * 16 + lrow) * K + lcol;
    const int wm = w * 32;
    const int po0 = (quad ^ (col & 7)) * 8;
    const int po1 = ((quad + 4) ^ (col & 7)) * 8;

    for (int kb = 0; kb < K; kb += 64) {
        __syncthreads();
        #pragma unroll
        for (int i = 0; i < 4; i++)
            GL2LDS16(Ag + (size_t)(i * 8) * K + kb, &As[(w * 32 + i * 8) * 64]);
        #pragma unroll
        for (int i = 0; i < 2; i++)
            GL2LDS16(Wg + (size_t)(i * 8) * K + kb, &Ws[(w * 16 + i * 8) * 64]);
        __syncthreads();

        #pragma unroll
        for (int s = 0; s < 2; s++) {
            const int po = s ? po1 : po0;
            short8 af[2], wf[4];
            #pragma unroll
            for (int t = 0; t < 2; t++)
                af[t] = *(const short8*)&As[(wm + t * 16 + col) * 64 + po];
            #pragma unroll
            for (int u = 0; u < 4; u++)
                wf[u] = *(const short8*)&Ws[(u * 16 + col) * 64 + po];
            #pragma unroll
            for (int t = 0; t < 2; t++)
                #pragma unroll
                for (int u = 0; u < 4; u++)
                    acc[t][u] = __builtin_amdgcn_mfma_f32_16x16x32_bf16(af[t], wf[u], acc[t][u], 0, 0, 0);
        }
    }

    #pragma unroll
    for (int u = 0; u < 4; u++) {
        const int n = n0 + u * 16 + col;
        const float bb = bias[n];
        #pragma unroll
        for (int t = 0; t < 2; t++) {
            const int mbase = m0 + wm + t * 16 + quad * 4;
            #pragma unroll
            for (int r = 0; r < 4; r++)
                out[(size_t)(mbase + r) * N + n] = acc[t][u][r] + bb;
        }
    }
}

// ---------------------------------------------------------------------------
// Fused flash attention, 32x32x16 MFMA, S^T formulation, IN-BLOCK k-split.
// Block: 256 thr = 4 waves = 2 q-halves (wq) x 2 k-halves (wk).
// q-tile 64, wave handles 32 q over k in [wk*1024, wk*1024+1024).
// After K-loop: wk=1 dumps acc+lsum to LDS (reusing Ks/Vts), wk=0 combines,
// normalizes by 1/(lsum+1e-8), writes bf16-swizzled Ohp. No global partials.
// Grid: 32 q-blocks x 32 bh = 1024 blocks.
// ---------------------------------------------------------------------------
__global__ __launch_bounds__(256, 4)
void attn6(const unsigned short* __restrict__ Qp,
           const unsigned short* __restrict__ Kp,
           const unsigned short* __restrict__ Vtp,
           const u64* __restrict__ Mb,
           unsigned short* __restrict__ Ohp) {
    constexpr int NQ = 2048, NK = 2048;
    __shared__ unsigned short Ks[2][64 * 64];    // [wk][k-row][d]
    __shared__ unsigned short Vts[2][64 * 64];   // [wk][d-row][tok]
    __shared__ unsigned short Pt[4][32 * 72];

    const int tid = threadIdx.x;
    const int w = tid >> 6, lane = tid & 63;
    const int wq = w & 1, wk = w >> 1;
    const int col = lane & 31, hi = lane >> 5, l7 = lane & 7;
    const int q0 = blockIdx.x * 64 + wq * 32;
    const int bh = blockIdx.y, b = bh >> 4, h = bh & 15;
    const int kbase = wk * (NK / 2);

    // Q B-operand fragments (q = col), Qp pre-scaled by log2e/32
    short8 qf[4];
    {
        const unsigned short* qrow =
            Qp + ((size_t)b * NQ + q0 + col) * 1024 + h * 64;
        #pragma unroll
        for (int c = 0; c < 4; c++)
            qf[c] = *(const short8*)(qrow + (((c * 2 + hi) ^ l7) * 8));
    }

    floatx16 acc0 = {0,0,0,0,0,0,0,0,0,0,0,0,0,0,0,0};
    floatx16 acc1 = {0,0,0,0,0,0,0,0,0,0,0,0,0,0,0,0};
    float ls = 0.f;

    const int lrow = lane >> 3, lcol = (lane & 7) * 8;
    // this wave stages rows [wq*32, wq*32+32) of its wk-half's K and V tiles
    const unsigned short* Kg =
        Kp + ((size_t)b * NK + kbase + wq * 32 + lrow) * 1024 + h * 64 + lcol;
    const unsigned short* Vg =
        Vtp + ((size_t)b * 1024 + h * 64 + wq * 32 + lrow) * NK + kbase + lcol;
    const u64* mq = Mb + ((size_t)b * NQ + q0 + col) * 32;

    for (int k0 = 0; k0 < NK / 2; k0 += 64) {
        __syncthreads();
        #pragma unroll
        for (int i = 0; i < 4; i++) {
            GL2LDS16(Kg + (size_t)(k0 + i * 8) * 1024, &Ks[wk][(wq * 32 + i * 8) * 64]);
            GL2LDS16(Vg + (size_t)(i * 8) * NK + k0,   &Vts[wk][(wq * 32 + i * 8) * 64]);
        }
        const u64 mw = mq[(kbase + k0) >> 6];
        __syncthreads();

        // S^T: col = q, rows = k (rg*8 + 4*hi + r)
        #pragma unroll
        for (int g = 0; g < 2; g++) {
            floatx16 s = {0,0,0,0,0,0,0,0,0,0,0,0,0,0,0,0};
            #pragma unroll
            for (int c = 0; c < 4; c++) {
                short8 kf = *(const short8*)&Ks[wk][(g * 32 + col) * 64 + (((c * 2 + hi) ^ l7) * 8)];
                s = __builtin_amdgcn_mfma_f32_32x32x16_bf16(kf, qf[c], s, 0, 0, 0);
            }
            const unsigned wbits = (unsigned)(mw >> (g * 32));
            #pragma unroll
            for (int rg = 0; rg < 4; rg++) {
                const unsigned b4 = (wbits >> (rg * 8 + 4 * hi)) & 0xFu;
                const float p0 = (b4 & 1u) ? __builtin_amdgcn_exp2f(s[rg * 4 + 0]) : 0.f;
                const float p1 = (b4 & 2u) ? __builtin_amdgcn_exp2f(s[rg * 4 + 1]) : 0.f;
                const float p2 = (b4 & 4u) ? __builtin_amdgcn_exp2f(s[rg * 4 + 2]) : 0.f;
                const float p3 = (b4 & 8u) ? __builtin_amdgcn_exp2f(s[rg * 4 + 3]) : 0.f;
                ls += (p0 + p1) + (p2 + p3);
                uint2 pk;
                pk.x = pack_bf16x2(p0, p1);
                pk.y = pack_bf16x2(p2, p3);
                *(uint2*)&Pt[w][col * 72 + g * 32 + rg * 8 + 4 * hi] = pk;
            }
        }
        // Pt is wave-private; same-wave DS ordering covers write->read

        // O += P V
        #pragma unroll
        for (int kc = 0; kc < 4; kc++) {
            short8 pf = *(const short8*)&Pt[w][col * 72 + kc * 16 + hi * 8];
            short8 vf0 = *(const short8*)&Vts[wk][col * 64 + (((kc * 2 + hi) ^ l7) * 8)];
            acc0 = __builtin_amdgcn_mfma_f32_32x32x16_bf16(pf, vf0, acc0, 0, 0, 0);
            short8 vf1 = *(const short8*)&Vts[wk][(32 + col) * 64 + (((kc * 2 + hi) ^ l7) * 8)];
            acc1 = __builtin_amdgcn_mfma_f32_32x32x16_bf16(pf, vf1, acc1, 0, 0, 0);
        }
    }

    // per-lane l: sum the two hi-halves (lane q = col)
    ls += __shfl_xor(ls, 32);

    // cross-wk reduction through LDS (reuse Ks as 2x32x64 f32, Vts head as l)
    __syncthreads();
    float* Racc = (float*)&Ks[0][0];   // [wq][q(32)][d(64)] : exactly 16 KB
    float* Rl   = (float*)&Vts[0][0];  // [wq*32 + q] : 256 B

    if (wk == 1) {
        #pragma unroll
        for (int rg = 0; rg < 4; rg++)
            #pragma unroll
            for (int r = 0; r < 4; r++) {
                const int q = rg * 8 + 4 * hi + r;
                Racc[(wq * 32 + q) * 64 + col]      = acc0[rg * 4 + r];
                Racc[(wq * 32 + q) * 64 + 32 + col] = acc1[rg * 4 + r];
            }
        if (hi == 0) Rl[wq * 32 + col] = ls;
    }
    __syncthreads();
    if (wk == 0) {
        const float ltot = ls + Rl[wq * 32 + col];
        const float inv = 1.0f / (ltot + 1e-8f);
        #pragma unroll
        for (int rg = 0; rg < 4; rg++)
            #pragma unroll
            for (int r = 0; r < 4; r++) {
                const int q = rg * 8 + 4 * hi + r;
                const float a0 = acc0[rg * 4 + r] + Racc[(wq * 32 + q) * 64 + col];
                const float a1 = acc1[rg * 4 + r] + Racc[(wq * 32 + q) * 64 + 32 + col];
                const float invq = __shfl(inv, q);
                const int qg = q & 7;   // q0 is a multiple of 32 -> global q & 7 == q & 7
                unsigned short* orow =
                    Ohp + ((size_t)b * NQ + q0 + q) * 1024 + h * 64;
                const int g0 = col >> 3, g1 = 4 + (col >> 3);
                orow[((g0 ^ qg) * 8) + l7] = f32_to_bf16(a0 * invq);
                orow[((g1 ^ qg) * 8) + l7] = f32_to_bf16(a1 * invq);
            }
    }
}

extern "C" void kernel_launch(void* const* d_in, const int* in_sizes, int n_in,
                              void* d_out, int out_size, void* d_ws, size_t ws_size,
                              hipStream_t stream) {
    const float* Q    = (const float*)d_in[0];
    const float* K    = (const float*)d_in[1];
    const int*   mask = (const int*)d_in[2];
    const float* Wq   = (const float*)d_in[3];
    const float* bq   = (const float*)d_in[4];
    const float* Wk   = (const float*)d_in[5];
    const float* bk   = (const float*)d_in[6];
    const float* Wv   = (const float*)d_in[7];
    const float* bv   = (const float*)d_in[8];
    const float* Wo   = (const float*)d_in[9];
    const float* bo   = (const float*)d_in[10];
    float* out = (float*)d_out;

    constexpr int M = 2 * 2048;
    constexpr size_t MB8 = (size_t)M * 1024 * sizeof(unsigned short);      // 8 MB
    constexpr size_t MB2 = (size_t)1024 * 1024 * sizeof(unsigned short);   // 2 MB

    char* ws = (char*)d_ws;
    unsigned short* Qc  = (unsigned short*)(ws);              // dead after proj3; reused as Ohp
    unsigned short* Ohp = (unsigned short*)(ws);
    unsigned short* Kc  = (unsigned short*)(ws + MB8);
    unsigned short* Wqc = (unsigned short*)(ws + 2 * MB8);
    unsigned short* Wkc = (unsigned short*)(ws + 2 * MB8 + MB2);
    unsigned short* Wvc = (unsigned short*)(ws + 2 * MB8 + 2 * MB2);
    unsigned short* Woc = (unsigned short*)(ws + 2 * MB8 + 3 * MB2);
    unsigned short* Qp  = (unsigned short*)(ws + 2 * MB8 + 4 * MB2);
    unsigned short* Kp  = (unsigned short*)(ws + 3 * MB8 + 4 * MB2);
    unsigned short* Vtp = (unsigned short*)(ws + 4 * MB8 + 4 * MB2);
    u64*            Mb  = (u64*)(ws + 5 * MB8 + 4 * MB2);

    dim3 blk(256);

    // conversions + mask bitpack, one launch
    prep<<<dim3(12288 + 32768), blk, 0, stream>>>(
        Q, K, Wq, Wk, Wv, Wo, mask, Qc, Kc, Wqc, Wkc, Wvc, Woc, Mb);

    // projections
    proj3<<<dim3(M / 128, 1024 / 128, 3), blk, 0, stream>>>(
        Qc, Kc, Wqc, Wkc, Wvc, bq, bk, bv, Qp, Kp, Vtp);

    // fused attention (in-block k-split, no global partials)
    attn6<<<dim3(2048 / 64, 32), blk, 0, stream>>>(Qp, Kp, Vtp, Mb, Ohp);

    // output projection
    gemm_o<<<dim3(M / 128, 1024 / 64), blk, 0, stream>>>(Ohp, Woc, bo, out);
}

// Round 8
// 253.498 us; speedup vs baseline: 1.0515x; 1.0515x over previous
//
#include <hip/hip_runtime.h>
#include <hip/hip_bf16.h>
#include <math.h>

typedef __attribute__((ext_vector_type(8))) short short8;
typedef __attribute__((ext_vector_type(4))) float floatx4;
typedef __attribute__((ext_vector_type(16))) float floatx16;
typedef __attribute__((ext_vector_type(4))) unsigned short ushort4v;
typedef unsigned long long u64;

__device__ __forceinline__ unsigned short f32_to_bf16(float f) {
    union { float f; unsigned int u; } v; v.f = f;
    return (unsigned short)((v.u + 0x7fffu + ((v.u >> 16) & 1u)) >> 16);
}
__device__ __forceinline__ unsigned pack_bf16x2(float a, float b) {
    __hip_bfloat162 h = __float22bfloat162_rn(make_float2(a, b));
    union { __hip_bfloat162 h; unsigned u; } c; c.h = h; return c.u;
}

#define GL2LDS16(g, l)                                                        \
    __builtin_amdgcn_global_load_lds(                                         \
        (const __attribute__((address_space(1))) unsigned int*)(g),           \
        (__attribute__((address_space(3))) unsigned int*)(l), 16, 0, 0)

// XOR-swizzle: within each 64-elem chunk, physical 8-group = logical ^ (row&7)
__device__ __forceinline__ int swz(int k, int row) {
    return (k & ~63) | (k & 7) | ((((k >> 3) ^ row) & 7) << 3);
}

// log2(e)/32: folds exp->exp2 and the 1/sqrt(1024) scale into Q
#define QSCALE 0.04508422002f

// ---------------------------------------------------------------------------
// prep: six f32->bf16 swizzled conversions AND mask->bitmask, one launch.
// ---------------------------------------------------------------------------
__global__ __launch_bounds__(256)
void prep(const float* __restrict__ Q, const float* __restrict__ K,
          const float* __restrict__ Wq, const float* __restrict__ Wk,
          const float* __restrict__ Wv, const float* __restrict__ Wo,
          const int* __restrict__ mask,
          unsigned short* __restrict__ Qc, unsigned short* __restrict__ Kc,
          unsigned short* __restrict__ Wqc, unsigned short* __restrict__ Wkc,
          unsigned short* __restrict__ Wvc, unsigned short* __restrict__ Woc,
          u64* __restrict__ Mb) {
    const int r = blockIdx.x;
    if (r < 12288) {
        const float* src; unsigned short* dst; int row;
        if (r < 4096)      { src = Q; dst = Qc; row = r; }
        else if (r < 8192) { src = K; dst = Kc; row = r - 4096; }
        else {
            const int t = r - 8192; const int wi = t >> 10; row = t & 1023;
            src = (wi == 0) ? Wq : (wi == 1) ? Wk : (wi == 2) ? Wv : Wo;
            dst = (wi == 0) ? Wqc : (wi == 1) ? Wkc : (wi == 2) ? Wvc : Woc;
        }
        const int k = threadIdx.x * 4;
        floatx4 v = *(const floatx4*)(src + (size_t)row * 1024 + k);
        ushort4v o;
        #pragma unroll
        for (int j = 0; j < 4; j++) o[j] = f32_to_bf16(v[j]);
        *(ushort4v*)(dst + (size_t)row * 1024 + swz(k, row)) = o;
    } else {
        const int gid = (r - 12288) * 256 + threadIdx.x;
        const int v = mask[gid];
        u64 bal = __ballot(v != 0);
        if ((threadIdx.x & 63) == 0) Mb[gid >> 6] = bal;
    }
}

// ---------------------------------------------------------------------------
// Three projection GEMMs, one launch (grid.z): m97 structure — 128x128 tile,
// BK=64, 16x16x32 MFMA, 4x4 acc tiles per wave (32 MFMA : 16 b128 / BK-step).
// z=0: Qp = (Qc Wq^T + bq) * QSCALE; z=1: Kp; z=2: Vtp (transposed out).
// gemm_o stays 128x64 (isolating this change; r4 coupled both and regressed).
// ---------------------------------------------------------------------------
__global__ __launch_bounds__(256)
void proj3(const unsigned short* __restrict__ Qc, const unsigned short* __restrict__ Kc,
           const unsigned short* __restrict__ Wq, const unsigned short* __restrict__ Wk,
           const unsigned short* __restrict__ Wv,
           const float* __restrict__ bq, const float* __restrict__ bk,
           const float* __restrict__ bv,
           unsigned short* __restrict__ Qp, unsigned short* __restrict__ Kp,
           unsigned short* __restrict__ Vtp) {
    constexpr int K = 1024;
    const int z = blockIdx.z;
    const unsigned short* A = (z == 0) ? Qc : Kc;
    const unsigned short* W = (z == 0) ? Wq : (z == 1) ? Wk : Wv;
    const float* bias = (z == 0) ? bq : (z == 1) ? bk : bv;

    __shared__ unsigned short As[128 * 64];
    __shared__ unsigned short Ws[128 * 64];

    const int tid = threadIdx.x;
    const int w = tid >> 6, lane = tid & 63;
    const int col = lane & 15, quad = lane >> 4;
    const int m0 = blockIdx.x * 128, n0 = blockIdx.y * 128;
    const int wm = (w >> 1) * 64, wn = (w & 1) * 64;

    floatx4 acc[4][4];
    #pragma unroll
    for (int t = 0; t < 4; t++)
        #pragma unroll
        for (int u = 0; u < 4; u++) acc[t][u] = (floatx4){0.f, 0.f, 0.f, 0.f};

    const int lrow = lane >> 3, lcol = (lane & 7) * 8;
    const unsigned short* Ag = A + (size_t)(m0 + w * 32 + lrow) * K + lcol;
    const unsigned short* Wg = W + (size_t)(n0 + w * 32 + lrow) * K + lcol;
    const int po0 = (quad ^ (col & 7)) * 8;
    const int po1 = ((quad + 4) ^ (col & 7)) * 8;

    for (int kb = 0; kb < K; kb += 64) {
        __syncthreads();
        #pragma unroll
        for (int i = 0; i < 4; i++) {
            GL2LDS16(Ag + (size_t)(i * 8) * K + kb, &As[(w * 32 + i * 8) * 64]);
            GL2LDS16(Wg + (size_t)(i * 8) * K + kb, &Ws[(w * 32 + i * 8) * 64]);
        }
        __syncthreads();

        #pragma unroll
        for (int s = 0; s < 2; s++) {
            const int po = s ? po1 : po0;
            short8 af[4], wf[4];
            #pragma unroll
            for (int t = 0; t < 4; t++)
                af[t] = *(const short8*)&As[(wm + t * 16 + col) * 64 + po];
            #pragma unroll
            for (int u = 0; u < 4; u++)
                wf[u] = *(const short8*)&Ws[(wn + u * 16 + col) * 64 + po];
            #pragma unroll
            for (int t = 0; t < 4; t++)
                #pragma unroll
                for (int u = 0; u < 4; u++)
                    acc[t][u] = __builtin_amdgcn_mfma_f32_16x16x32_bf16(af[t], wf[u], acc[t][u], 0, 0, 0);
        }
    }

    #pragma unroll
    for (int u = 0; u < 4; u++) {
        const int n = n0 + wn + u * 16 + col;
        const float bb = bias[n];
        const int ng = (n >> 3) & 7;
        #pragma unroll
        for (int t = 0; t < 4; t++) {
            const int mbase = m0 + wm + t * 16 + quad * 4;
            if (z == 2) {
                // Vtp[b][1024 d][2048 tokens], token dim swizzled by (d&7)
                const int bidx = mbase >> 11;
                const int tl = mbase & 2047;
                const int mg = (mbase >> 3) & 7;
                ushort4v o;
                #pragma unroll
                for (int r = 0; r < 4; r++)
                    o[r] = f32_to_bf16(acc[t][u][r] + bb);
                *(ushort4v*)(Vtp + ((size_t)(bidx * 1024 + n)) * 2048 +
                             (tl & ~63) + ((mg ^ (n & 7)) * 8) + (tl & 7)) = o;
            } else {
                unsigned short* outp = (z == 0) ? Qp : Kp;
                const float sc = (z == 0) ? QSCALE : 1.0f;
                #pragma unroll
                for (int r = 0; r < 4; r++) {
                    const int m = mbase + r;
                    const int pn = (n & ~63) | (((ng ^ (m & 7)) & 7) << 3) | (n & 7);
                    outp[(size_t)m * 1024 + pn] =
                        f32_to_bf16((acc[t][u][r] + bb) * sc);
                }
            }
        }
    }
}

// ---------------------------------------------------------------------------
// Output projection: f32 out, A/W bf16-swizzled. 128x64 tile (512 blocks).
// ---------------------------------------------------------------------------
__global__ __launch_bounds__(256)
void gemm_o(const unsigned short* __restrict__ A, const unsigned short* __restrict__ W,
            const float* __restrict__ bias, float* __restrict__ out) {
    constexpr int K = 1024, N = 1024;
    __shared__ unsigned short As[128 * 64];
    __shared__ unsigned short Ws[64 * 64];

    const int tid = threadIdx.x;
    const int w = tid >> 6, lane = tid & 63;
    const int col = lane & 15, quad = lane >> 4;
    const int m0 = blockIdx.x * 128, n0 = blockIdx.y * 64;

    floatx4 acc[2][4];
    #pragma unroll
    for (int t = 0; t < 2; t++)
        #pragma unroll
        for (int u = 0; u < 4; u++) acc[t][u] = (floatx4){0.f, 0.f, 0.f, 0.f};

    const int lrow = lane >> 3, lcol = (lane & 7) * 8;
    const unsigned short* Ag = A + (size_t)(m0 + w * 32 + lrow) * K + lcol;
    const unsigned short* Wg = W + (size_t)(n0 + w * 16 + lrow) * K + lcol;
    const int wm = w * 32;
    const int po0 = (quad ^ (col & 7)) * 8;
    const int po1 = ((quad + 4) ^ (col & 7)) * 8;

    for (int kb = 0; kb < K; kb += 64) {
        __syncthreads();
        #pragma unroll
        for (int i = 0; i < 4; i++)
            GL2LDS16(Ag + (size_t)(i * 8) * K + kb, &As[(w * 32 + i * 8) * 64]);
        #pragma unroll
        for (int i = 0; i < 2; i++)
            GL2LDS16(Wg + (size_t)(i * 8) * K + kb, &Ws[(w * 16 + i * 8) * 64]);
        __syncthreads();

        #pragma unroll
        for (int s = 0; s < 2; s++) {
            const int po = s ? po1 : po0;
            short8 af[2], wf[4];
            #pragma unroll
            for (int t = 0; t < 2; t++)
                af[t] = *(const short8*)&As[(wm + t * 16 + col) * 64 + po];
            #pragma unroll
            for (int u = 0; u < 4; u++)
                wf[u] = *(const short8*)&Ws[(u * 16 + col) * 64 + po];
            #pragma unroll
            for (int t = 0; t < 2; t++)
                #pragma unroll
                for (int u = 0; u < 4; u++)
                    acc[t][u] = __builtin_amdgcn_mfma_f32_16x16x32_bf16(af[t], wf[u], acc[t][u], 0, 0, 0);
        }
    }

    #pragma unroll
    for (int u = 0; u < 4; u++) {
        const int n = n0 + u * 16 + col;
        const float bb = bias[n];
        #pragma unroll
        for (int t = 0; t < 2; t++) {
            const int mbase = m0 + wm + t * 16 + quad * 4;
            #pragma unroll
            for (int r = 0; r < 4; r++)
                out[(size_t)(mbase + r) * N + n] = acc[t][u][r] + bb;
        }
    }
}

// ---------------------------------------------------------------------------
// Fused flash attention, 32x32x16 MFMA, S^T formulation, split-K=2 (grid.z).
// (r5's attn5 — measured 62 us; r7's in-block split regressed, reverted.)
// ---------------------------------------------------------------------------
__global__ __launch_bounds__(256, 4)
void attn5(const unsigned short* __restrict__ Qp,
           const unsigned short* __restrict__ Kp,
           const unsigned short* __restrict__ Vtp,
           const u64* __restrict__ Mb,
           float* __restrict__ Oacc, float* __restrict__ Lsum) {
    constexpr int NQ = 2048, NK = 2048;
    __shared__ unsigned short Ks[64 * 64];
    __shared__ unsigned short Vts[64 * 64];
    __shared__ unsigned short Pt[4][32 * 72];

    const int tid = threadIdx.x;
    const int wq = tid >> 6, lane = tid & 63;
    const int col = lane & 31, hi = lane >> 5, l7 = lane & 7;
    const int q0 = blockIdx.x * 128;
    const int bh = blockIdx.y, b = bh >> 4, h = bh & 15;
    const int z = blockIdx.z;
    const int kbeg = z * (NK / 2), kend = kbeg + NK / 2;

    short8 qf[4];
    {
        const unsigned short* qrow =
            Qp + ((size_t)b * NQ + q0 + wq * 32 + col) * 1024 + h * 64;
        #pragma unroll
        for (int c = 0; c < 4; c++)
            qf[c] = *(const short8*)(qrow + (((c * 2 + hi) ^ l7) * 8));
    }

    floatx16 acc0 = {0,0,0,0,0,0,0,0,0,0,0,0,0,0,0,0};
    floatx16 acc1 = {0,0,0,0,0,0,0,0,0,0,0,0,0,0,0,0};
    float ls0 = 0.f, ls1 = 0.f;

    const int lrow = lane >> 3, lcol = (lane & 7) * 8;
    const unsigned short* Kg =
        Kp + ((size_t)b * NK + wq * 16 + lrow) * 1024 + h * 64 + lcol;
    const unsigned short* Vg =
        Vtp + ((size_t)b * 1024 + h * 64 + wq * 16 + lrow) * NK + lcol;
    const u64* mq = Mb + ((size_t)b * NQ + q0 + wq * 32 + col) * 32;

    for (int k0 = kbeg; k0 < kend; k0 += 64) {
        __syncthreads();
        GL2LDS16(Kg + (size_t)(k0) * 1024,     &Ks[(wq * 16) * 64]);
        GL2LDS16(Kg + (size_t)(k0 + 8) * 1024, &Ks[(wq * 16 + 8) * 64]);
        GL2LDS16(Vg + k0,                      &Vts[(wq * 16) * 64]);
        GL2LDS16(Vg + (size_t)8 * NK + k0,     &Vts[(wq * 16 + 8) * 64]);
        const u64 mw = mq[k0 >> 6];
        __syncthreads();

        #pragma unroll
        for (int g = 0; g < 2; g++) {
            floatx16 s = {0,0,0,0,0,0,0,0,0,0,0,0,0,0,0,0};
            #pragma unroll
            for (int c = 0; c < 4; c++) {
                short8 kf = *(const short8*)&Ks[(g * 32 + col) * 64 + (((c * 2 + hi) ^ l7) * 8)];
                s = __builtin_amdgcn_mfma_f32_32x32x16_bf16(kf, qf[c], s, 0, 0, 0);
            }
            const unsigned wbits = (unsigned)(mw >> (g * 32));
            #pragma unroll
            for (int rg = 0; rg < 4; rg++) {
                const unsigned b4 = (wbits >> (rg * 8 + 4 * hi)) & 0xFu;
                const float p0 = (b4 & 1u) ? __builtin_amdgcn_exp2f(s[rg * 4 + 0]) : 0.f;
                const float p1 = (b4 & 2u) ? __builtin_amdgcn_exp2f(s[rg * 4 + 1]) : 0.f;
                const float p2 = (b4 & 4u) ? __builtin_amdgcn_exp2f(s[rg * 4 + 2]) : 0.f;
                const float p3 = (b4 & 8u) ? __builtin_amdgcn_exp2f(s[rg * 4 + 3]) : 0.f;
                ls0 += p0 + p2;
                ls1 += p1 + p3;
                uint2 pk;
                pk.x = pack_bf16x2(p0, p1);
                pk.y = pack_bf16x2(p2, p3);
                *(uint2*)&Pt[wq][col * 72 + g * 32 + rg * 8 + 4 * hi] = pk;
            }
        }

        #pragma unroll
        for (int kc = 0; kc < 4; kc++) {
            short8 pf = *(const short8*)&Pt[wq][col * 72 + kc * 16 + hi * 8];
            short8 vf0 = *(const short8*)&Vts[col * 64 + (((kc * 2 + hi) ^ l7) * 8)];
            acc0 = __builtin_amdgcn_mfma_f32_32x32x16_bf16(pf, vf0, acc0, 0, 0, 0);
            short8 vf1 = *(const short8*)&Vts[(32 + col) * 64 + (((kc * 2 + hi) ^ l7) * 8)];
            acc1 = __builtin_amdgcn_mfma_f32_32x32x16_bf16(pf, vf1, acc1, 0, 0, 0);
        }
    }

    float lsum = ls0 + ls1;
    lsum += __shfl_xor(lsum, 32);

    const size_t base = ((size_t)(z * 32 + bh) * NQ + q0 + wq * 32) * 64;
    #pragma unroll
    for (int rg = 0; rg < 4; rg++)
        #pragma unroll
        for (int r = 0; r < 4; r++) {
            const int qrow = rg * 8 + 4 * hi + r;
            Oacc[base + (size_t)qrow * 64 + col]      = acc0[rg * 4 + r];
            Oacc[base + (size_t)qrow * 64 + 32 + col] = acc1[rg * 4 + r];
        }
    if (hi == 0)
        Lsum[(size_t)(z * 32 + bh) * NQ + q0 + wq * 32 + col] = lsum;
}

// ---------------------------------------------------------------------------
// Combine split-K halves: Ohp = (acc0+acc1) / (l0+l1+eps), bf16 swizzled.
// ---------------------------------------------------------------------------
__global__ __launch_bounds__(256)
void combine2(const float* __restrict__ Oacc, const float* __restrict__ Lsum,
              unsigned short* __restrict__ Ohp) {
    const int T = blockIdx.x * 256 + threadIdx.x;
    const int d0 = (T & 15) * 4;
    const int q = (T >> 4) & 2047;
    const int bh = T >> 15;
    const int b = bh >> 4, h = bh & 15;
    const size_t o0 = ((size_t)bh * 2048 + q) * 64 + d0;
    const size_t o1 = ((size_t)(32 + bh) * 2048 + q) * 64 + d0;
    floatx4 a0 = *(const floatx4*)(Oacc + o0);
    floatx4 a1 = *(const floatx4*)(Oacc + o1);
    const float l = Lsum[(size_t)bh * 2048 + q] + Lsum[(size_t)(32 + bh) * 2048 + q];
    const float inv = 1.0f / (l + 1e-8f);
    ushort4v o;
    #pragma unroll
    for (int j = 0; j < 4; j++) o[j] = f32_to_bf16((a0[j] + a1[j]) * inv);
    const int g = d0 >> 3, qg = q & 7;
    *(ushort4v*)(Ohp + ((size_t)b * 2048 + q) * 1024 + h * 64 +
                 ((g ^ qg) * 8) + (d0 & 7)) = o;
}

extern "C" void kernel_launch(void* const* d_in, const int* in_sizes, int n_in,
                              void* d_out, int out_size, void* d_ws, size_t ws_size,
                              hipStream_t stream) {
    const float* Q    = (const float*)d_in[0];
    const float* K    = (const float*)d_in[1];
    const int*   mask = (const int*)d_in[2];
    const float* Wq   = (const float*)d_in[3];
    const float* bq   = (const float*)d_in[4];
    const float* Wk   = (const float*)d_in[5];
    const float* bk   = (const float*)d_in[6];
    const float* Wv   = (const float*)d_in[7];
    const float* bv   = (const float*)d_in[8];
    const float* Wo   = (const float*)d_in[9];
    const float* bo   = (const float*)d_in[10];
    float* out = (float*)d_out;

    constexpr int M = 2 * 2048;
    constexpr size_t MB8 = (size_t)M * 1024 * sizeof(unsigned short);      // 8 MB
    constexpr size_t MB2 = (size_t)1024 * 1024 * sizeof(unsigned short);   // 2 MB
    constexpr size_t MBMASK = (size_t)2 * 2048 * 2048 / 64 * 8;            // 1 MB
    constexpr size_t BASE = 5 * MB8 + 4 * MB2 + MBMASK;
    constexpr size_t OACC_SZ = (size_t)2 * 32 * 2048 * 64 * 4;             // 33.5 MB
    constexpr size_t LSUM_SZ = (size_t)2 * 32 * 2048 * 4;                  // 0.5 MB

    char* ws = (char*)d_ws;
    unsigned short* Qc  = (unsigned short*)(ws);              // dead after proj3; reused as Ohp
    unsigned short* Ohp = (unsigned short*)(ws);
    unsigned short* Kc  = (unsigned short*)(ws + MB8);
    unsigned short* Wqc = (unsigned short*)(ws + 2 * MB8);
    unsigned short* Wkc = (unsigned short*)(ws + 2 * MB8 + MB2);
    unsigned short* Wvc = (unsigned short*)(ws + 2 * MB8 + 2 * MB2);
    unsigned short* Woc = (unsigned short*)(ws + 2 * MB8 + 3 * MB2);
    unsigned short* Qp  = (unsigned short*)(ws + 2 * MB8 + 4 * MB2);
    unsigned short* Kp  = (unsigned short*)(ws + 3 * MB8 + 4 * MB2);
    unsigned short* Vtp = (unsigned short*)(ws + 4 * MB8 + 4 * MB2);
    u64*            Mb  = (u64*)(ws + 5 * MB8 + 4 * MB2);
    float*          Oacc = (float*)(ws + BASE);
    float*          Lsum = (float*)(ws + BASE + OACC_SZ);

    dim3 blk(256);

    prep<<<dim3(12288 + 32768), blk, 0, stream>>>(
        Q, K, Wq, Wk, Wv, Wo, mask, Qc, Kc, Wqc, Wkc, Wvc, Woc, Mb);

    proj3<<<dim3(M / 128, 1024 / 128, 3), blk, 0, stream>>>(
        Qc, Kc, Wqc, Wkc, Wvc, bq, bk, bv, Qp, Kp, Vtp);

    attn5<<<dim3(2048 / 128, 32, 2), blk, 0, stream>>>(
        Qp, Kp, Vtp, Mb, Oacc, Lsum);
    combine2<<<dim3(2 * 32 * 2048 * 16 / 256 / 2), blk, 0, stream>>>(Oacc, Lsum, Ohp);

    gemm_o<<<dim3(M / 128, 1024 / 64), blk, 0, stream>>>(Ohp, Woc, bo, out);
}